// Round 17
// baseline (166.974 us; speedup 1.0000x reference)
//
#include <hip/hip_runtime.h>
#include <hip/hip_bf16.h>
#include <math.h>

#define D_MODEL 1024
#define NHEADS  16
#define DKH     64
#define BATCH   4
#define SEQ     2048
#define NTOK    (BATCH * SEQ)   // 8192
#define NELEM   ((size_t)NTOK * D_MODEL)  // 8388608

typedef __bf16 v8bf __attribute__((ext_vector_type(8)));
typedef float  v4f  __attribute__((ext_vector_type(4)));

__device__ __forceinline__ v8bf ld_bf16x8(const ushort* p) {
    union { uint4 u; v8bf b; } cv;
    cv.u = *(const uint4*)p;
    return cv.b;
}
__device__ __forceinline__ ushort f2bf(float f) {
    __hip_bfloat16 h = __float2bfloat16(f);
    return *(ushort*)&h;
}
// hardware packed f32x2 -> bf16x2 (RNE), single VALU op
__device__ __forceinline__ uint cvt_pk_bf16(float lo, float hi) {
    uint r;
    asm("v_cvt_pk_bf16_f32 %0, %1, %2" : "=v"(r) : "v"(lo), "v"(hi));
    return r;
}

#define GLOAD_LDS16(gsrc, ldst)                                            \
    __builtin_amdgcn_global_load_lds(                                      \
        (const __attribute__((address_space(1))) void*)(gsrc),             \
        (__attribute__((address_space(3))) void*)(ldst), 16, 0, 0)

#define RAW_BARRIER() __builtin_amdgcn_s_barrier()

// ---------------- block reduce (256 threads = 4 waves) ----------------
__device__ __forceinline__ float block_reduce_sum(float v, float* sbuf) {
    #pragma unroll
    for (int off = 32; off > 0; off >>= 1)
        v += __shfl_xor(v, off, 64);
    int lane = threadIdx.x & 63;
    int wid  = threadIdx.x >> 6;
    if (lane == 0) sbuf[wid] = v;
    __syncthreads();
    float total = sbuf[0] + sbuf[1] + sbuf[2] + sbuf[3];
    __syncthreads();
    return total;
}

// ---------------- mega prep: all input prep in ONE launch --------------------
// blocks [0,8192):      x -> bf16 cast + per-row lam = 2/(1-|x|^2)
// blocks [8192,8704):   zq/zk transpose-cast into Wcat rows [0,2048)
// blocks [8704,9216):   w_v cast into Wcat rows [2048,3072)
// blocks [9216,11264):  per-column constants c1/sh/tz for q and k chains
__global__ __launch_bounds__(256) void mega_prep(const float* __restrict__ x,
                                                 const float* __restrict__ z_q,
                                                 const float* __restrict__ r_q,
                                                 const float* __restrict__ z_k,
                                                 const float* __restrict__ r_k,
                                                 const float* __restrict__ w_v,
                                                 ushort* __restrict__ xb,
                                                 float* __restrict__ lam,
                                                 ushort* __restrict__ Wcat,
                                                 float* __restrict__ aux) {
    __shared__ float tile[64][65];
    __shared__ float sbuf[4];
    int bid = blockIdx.x;
    int t = threadIdx.x;

    if (bid < 8192) {
        // ---- cast_x_lam ----
        int n = bid;
        const float* xr = x + (size_t)n * D_MODEL;
        float4 v = *(const float4*)&xr[t * 4];
        float s = v.x * v.x + v.y * v.y + v.z * v.z + v.w * v.w;
        float xn2 = block_reduce_sum(s, sbuf);
        if (t == 0) lam[n] = 2.f / (1.f - xn2);
        ushort u[4] = {f2bf(v.x), f2bf(v.y), f2bf(v.z), f2bf(v.w)};
        *(uint2*)&xb[(size_t)n * D_MODEL + t * 4] = *(uint2*)u;
    } else if (bid < 8704) {
        // ---- cast_transpose: zT[m][k] = z[k][m] ----
        int idx = bid - 8192;
        int zsel = idx >> 8;
        int rem = idx & 255;
        int m0 = (rem & 15) * 64, k0 = (rem >> 4) * 64;
        const float* z = zsel ? z_k : z_q;
        ushort* zT = Wcat + (size_t)zsel * D_MODEL * D_MODEL;
        #pragma unroll
        for (int i = 0; i < 4; ++i) {
            int r = (t >> 4) + 16 * i;
            int c = (t & 15) * 4;
            float4 v = *(const float4*)&z[(size_t)(k0 + r) * D_MODEL + m0 + c];
            tile[r][c + 0] = v.x; tile[r][c + 1] = v.y;
            tile[r][c + 2] = v.z; tile[r][c + 3] = v.w;
        }
        __syncthreads();
        #pragma unroll
        for (int i = 0; i < 2; ++i) {
            int idx2 = t + 256 * i;
            int r = idx2 >> 3;
            int c8 = idx2 & 7;
            ushort u[8];
            #pragma unroll
            for (int j = 0; j < 8; ++j)
                u[j] = f2bf(tile[c8 * 8 + j][r]);
            *(uint4*)&zT[(size_t)(m0 + r) * D_MODEL + k0 + c8 * 8] = *(uint4*)u;
        }
    } else if (bid < 9216) {
        // ---- cast_bf16 of w_v into Wcat rows [2048,3072) ----
        size_t i = ((size_t)(bid - 8704) * 256 + t) * 8;
        float4 a = *(const float4*)(w_v + i);
        float4 b = *(const float4*)(w_v + i + 4);
        ushort u[8] = {f2bf(a.x), f2bf(a.y), f2bf(a.z), f2bf(a.w),
                       f2bf(b.x), f2bf(b.y), f2bf(b.z), f2bf(b.w)};
        *(uint4*)(Wcat + (size_t)2 * D_MODEL * D_MODEL + i) = *(uint4*)u;
    } else {
        // ---- prep: c1 = cosh(2r)/||z_col||, sh = sinh(2r), tz = 2*||z_col|| ----
        int idx = bid - 9216;
        int which = idx >> 10;
        int m = idx & 1023;
        const float* z = which ? z_k : z_q;
        const float* r = which ? r_k : r_q;
        float* base = aux + which * 3072;
        float s = 0.f;
        for (int k = t; k < D_MODEL; k += 256) {
            float zv = z[k * D_MODEL + m];
            s += zv * zv;
        }
        float tot = block_reduce_sum(s, sbuf);
        if (t == 0) {
            float n = fmaxf(sqrtf(tot), 1e-15f);
            float tc = 2.f * r[m];   // c_sqrt = 1
            base[m]        = coshf(tc) / n;
            base[1024 + m] = sinhf(tc);
            base[2048 + m] = 2.f * n;
        }
    }
}

// ---------------- fused bf16 MFMA GEMM: C[8192,3072] = xb @ Wcat^T ------------
// R13 winner + s_setprio on the MFMA cluster (T5: ring waves have role split --
// load-issuing vs MFMA-entering -- setprio lets the scheduler favor the latter).
// 128x128 tile, BK=64, 2-buffer LDS ring + counted vmcnt + RAW barriers +
// both-sides XOR swizzle (0 conflicts measured).
// Chunk 0 -> bf16 Pq, chunk 1 -> bf16 Pk (d_out scratch), chunk 2 -> bf16 VT.
__global__ __launch_bounds__(256) void gemm_fused(const ushort* __restrict__ A,
                                                  const ushort* __restrict__ W,
                                                  const float* __restrict__ bias,
                                                  ushort* __restrict__ Pq,
                                                  ushort* __restrict__ Pk,
                                                  ushort* __restrict__ VT) {
    const int K = 1024;
    __shared__ ushort As[2][128][64];   // 32KB
    __shared__ ushort Bs[2][128][64];   // 32KB
    int tid = threadIdx.x;
    int w = tid >> 6, l = tid & 63;
    int lr = l & 15, lg = l >> 4;
    int wr = w >> 1, wc = w & 1;
    // XCD swizzle + L2 window: per XCD, groups of 32 t cover 8 M-tiles x 4 N-tiles
    int bid = blockIdx.x;
    int xcd = bid & 7, t = bid >> 3;                 // t in 0..191
    int m0 = (xcd * 8 + ((t >> 2) & 7)) * 128;
    int n0 = ((t >> 5) * 4 + (t & 3)) * 128;

    v4f acc[4][4];
    #pragma unroll
    for (int i = 0; i < 4; ++i)
        #pragma unroll
        for (int j = 0; j < 4; ++j)
            acc[i][j] = (v4f){0.f, 0.f, 0.f, 0.f};

    int srow = w * 32 + (l >> 3);
    // pre-swizzled source chunk: LDS row r holds chunk c at position c ^ (r&7)
    int scol = ((l & 7) ^ ((l >> 3) & 7)) * 8;

#define STAGE_G(buf, k0) do {                                                 \
        _Pragma("unroll")                                                     \
        for (int j = 0; j < 4; ++j) {                                         \
            GLOAD_LDS16(A + (size_t)(m0 + srow + j * 8) * K + (k0) + scol,    \
                        &As[buf][w * 32 + j * 8][0]);                         \
            GLOAD_LDS16(W + (size_t)(n0 + srow + j * 8) * K + (k0) + scol,    \
                        &Bs[buf][w * 32 + j * 8][0]);                         \
        }                                                                     \
    } while (0)

    int swz = (lr & 7) << 4;   // read-side XOR (row&7 == lr&7 for all fragments)

    STAGE_G(0, 0);
    for (int k0 = 0; k0 < K; k0 += 64) {
        int cur = (k0 >> 6) & 1;
        if (k0 + 64 < K) {
            STAGE_G(cur ^ 1, k0 + 64);                    // 8 loads in flight
            asm volatile("s_waitcnt vmcnt(8)" ::: "memory");  // cur's landed
        } else {
            asm volatile("s_waitcnt vmcnt(0)" ::: "memory");
        }
        RAW_BARRIER();
        __builtin_amdgcn_s_setprio(1);
        #pragma unroll
        for (int kk = 0; kk < 2; ++kk) {
            v8bf av[4], bv[4];
            #pragma unroll
            for (int i = 0; i < 4; ++i)
                av[i] = *(const v8bf*)((const char*)&As[cur][wr * 64 + i * 16 + lr][0]
                                       + ((kk * 64 + lg * 16) ^ swz));
            #pragma unroll
            for (int j = 0; j < 4; ++j)
                bv[j] = *(const v8bf*)((const char*)&Bs[cur][wc * 64 + j * 16 + lr][0]
                                       + ((kk * 64 + lg * 16) ^ swz));
            #pragma unroll
            for (int i = 0; i < 4; ++i)
                #pragma unroll
                for (int j = 0; j < 4; ++j)
                    acc[i][j] = __builtin_amdgcn_mfma_f32_16x16x32_bf16(av[i], bv[j], acc[i][j], 0, 0, 0);
        }
        __builtin_amdgcn_s_setprio(0);
        RAW_BARRIER();
    }
#undef STAGE_G

    int chunk = n0 >> 10;          // 0,1,2 (uniform per block)
    // D layout: lane holds col=lr, rows 4*lg+reg (reg 0..3 consecutive)
    #pragma unroll
    for (int i = 0; i < 4; ++i) {
        #pragma unroll
        for (int j = 0; j < 4; ++j) {
            int col = n0 + wc * 64 + j * 16 + lr;
            int cl  = col & 1023;  // column within chunk
            if (chunk < 2) {
                ushort* P = chunk ? Pk : Pq;
                #pragma unroll
                for (int reg = 0; reg < 4; ++reg) {
                    int row = m0 + wr * 64 + i * 16 + 4 * lg + reg;
                    P[(size_t)row * D_MODEL + cl] = f2bf(acc[i][j][reg]);
                }
            } else {
                float badd = bias[cl];
                int hh = cl >> 6, dk = cl & 63;
                int row = m0 + wr * 64 + i * 16 + 4 * lg;   // 4 consecutive tokens
                int bb = row >> 11, ss = row & 2047;
                // attention key-permutation (bit shuffle, preserves low 2 bits)
                int sp = (ss & ~63) | (ss & 0x23) | ((ss & 0x0C) << 1) | ((ss & 0x10) >> 2);
                ushort u[4];
                #pragma unroll
                for (int reg = 0; reg < 4; ++reg)
                    u[reg] = f2bf(acc[i][j][reg] + badd);
                *(uint2*)&VT[(((size_t)(bb * NHEADS + hh)) * DKH + dk) * SEQ + sp] = *(uint2*)u;
            }
        }
    }
}

// ---------------- Poincare epilogue (fast-math closed form, bf16 P in) -------
__global__ __launch_bounds__(256) void poincare_epilogue2(const ushort* __restrict__ Pq,
                                                          const ushort* __restrict__ Pk,
                                                          const float* __restrict__ lam_,
                                                          const float* __restrict__ aux,
                                                          ushort* __restrict__ Qb,
                                                          ushort* __restrict__ Kb) {
    __shared__ float sbuf[4];
    int which = blockIdx.y;
    const ushort* P  = which ? Pk : Pq;
    ushort* outb     = which ? Kb : Qb;
    const float* c1_ = aux + which * 3072;
    const float* sh_ = c1_ + 1024;
    const float* tz_ = c1_ + 2048;
    float oscale = which ? 1.0f : 0.1803368801f;  // K: 1; Q: log2(e)/8

    int n = blockIdx.x;
    float lam = lam_[n];
    float lm1 = lam - 1.f;
    int o = threadIdx.x * 4;
    uint2 pu = *(const uint2*)&P[(size_t)n * D_MODEL + o];
    float4 c1 = *(const float4*)&c1_[o];
    float4 sh = *(const float4*)&sh_[o];
    float4 tz = *(const float4*)&tz_[o];
    float pv[4];
    pv[0] = __uint_as_float(pu.x << 16);
    pv[1] = __uint_as_float(pu.x & 0xffff0000u);
    pv[2] = __uint_as_float(pu.y << 16);
    pv[3] = __uint_as_float(pu.y & 0xffff0000u);
    float c1v[4] = {c1.x, c1.y, c1.z, c1.w};
    float shv[4] = {sh.x, sh.y, sh.z, sh.w};
    float tzv[4] = {tz.x, tz.y, tz.z, tz.w};
    float w[4];
    float wn2 = 0.f;
    #pragma unroll
    for (int i = 0; i < 4; ++i) {
        float t  = fmaf(lam * c1v[i], pv[i], -lm1 * shv[i]);
        float at = fabsf(t);
        float u  = at + __builtin_amdgcn_sqrtf(fmaf(at, at, 1.f));
        float tl = tzv[i] * __builtin_amdgcn_logf(u);       // tz * log2(u)
        float e  = __builtin_amdgcn_exp2f(tl);
        float em = __builtin_amdgcn_exp2f(-tl);
        float wa = 0.5f * (e - em);
        w[i] = copysignf(wa, t);
        wn2 = fmaf(wa, wa, wn2);
    }
    wn2 = block_reduce_sum(wn2, sbuf);
    float invd = oscale / (1.f + __builtin_amdgcn_sqrtf(1.f + wn2));
    uint2 st;
    st.x = cvt_pk_bf16(w[0] * invd, w[1] * invd);
    st.y = cvt_pk_bf16(w[2] * invd, w[3] * invd);
    *(uint2*)&outb[(size_t)n * D_MODEL + o] = st;
}

// ---------------- MFMA attention (R9 structure + RAW barriers) ---------------
// 8 waves x 2 strips = 256 q/block, 512 blocks. P stays in registers
// (V key-permuted in global). den via MFMA vs ones. exp2 native.
// 4-deep LDS ring + counted vmcnt; raw s_barrier so prefetch STAYS in flight.
__global__ __launch_bounds__(512, 4) void attn_mfma(const ushort* __restrict__ Qb,
                                                    const ushort* __restrict__ Kb,
                                                    const ushort* __restrict__ VT,
                                                    float* __restrict__ Out) {
    __shared__ ushort Klds[4][64 * 64];   // [key][dk], chunk pos = c8 ^ (key&7)
    __shared__ ushort Vlds[4][64 * 64];   // [dk][keypos], chunk pos = c8 ^ (dk&7)

    int tid = threadIdx.x;
    int w = tid >> 6, l = tid & 63;
    int lr = l & 15, lg = l >> 4;

    // XCD swizzle: 512 blocks; xcd = flat&7 owns 8 (b,h) groups x 8 q-tiles
    int flat = blockIdx.x;
    int low3 = flat & 7;
    int rest = flat >> 3;            // 0..63
    int qx   = rest & 7;             // q-tile 0..7 (256 rows each)
    int g    = (rest & ~7) | low3;   // (b,h) 0..63
    int h = g & 15, b = g >> 4;

    const ushort* Kh = Kb + (size_t)b * SEQ * D_MODEL + h * DKH;
    const ushort* Vh = VT + (size_t)(b * NHEADS + h) * DKH * SEQ;

    // Q fragments for 2 strips (scale log2e/8 folded at epilogue); q = lr
    const ushort* qp0 = Qb + (size_t)b * SEQ * D_MODEL + h * DKH
                      + (size_t)(qx * 256 + w * 32 + lr) * D_MODEL;
    const ushort* qp1 = qp0 + (size_t)16 * D_MODEL;
    v8bf qa[2][2];
    qa[0][0] = ld_bf16x8(qp0 + lg * 8);
    qa[0][1] = ld_bf16x8(qp0 + 32 + lg * 8);
    qa[1][0] = ld_bf16x8(qp1 + lg * 8);
    qa[1][1] = ld_bf16x8(qp1 + 32 + lg * 8);

    // staging: 1 K-DMA + 1 V-DMA per thread per stage, pre-swizzled source
    int row = tid >> 3;                       // 0..63
    int c8  = (tid & 7) ^ (row & 7);
    const ushort* kg = Kh + (size_t)row * D_MODEL + c8 * 8;
    const ushort* vg = Vh + (size_t)row * SEQ + c8 * 8;

#define STAGE_KV(buf, st)  do {                                              \
        GLOAD_LDS16(kg + (size_t)(st) * 64 * D_MODEL, &Klds[buf][tid * 8]);  \
        GLOAD_LDS16(vg + (st) * 64, &Vlds[buf][tid * 8]);                    \
    } while (0)

    v4f o[2][4];
    v4f den4[2];
    #pragma unroll
    for (int st = 0; st < 2; ++st) {
        den4[st] = (v4f){0.f, 0.f, 0.f, 0.f};
        #pragma unroll
        for (int i = 0; i < 4; ++i) o[st][i] = (v4f){0.f, 0.f, 0.f, 0.f};
    }
    union { uint u[4]; v8bf v; } ones;
    ones.u[0] = ones.u[1] = ones.u[2] = ones.u[3] = 0x3f803f80u;

    auto compute = [&](int buf) {
        const char* Kc = (const char*)&Klds[buf][0];
        const char* Vc = (const char*)&Vlds[buf][0];

        // ---- QK^T swapped, both strips share each K fragment ----
        v4f sc[2][4];
        #pragma unroll
        for (int st = 0; st < 2; ++st)
            #pragma unroll
            for (int i = 0; i < 4; ++i) sc[st][i] = (v4f){0.f, 0.f, 0.f, 0.f};
        __builtin_amdgcn_s_setprio(1);
        #pragma unroll
        for (int f = 0; f < 2; ++f) {
            #pragma unroll
            for (int sub = 0; sub < 4; ++sub) {
                int key = sub * 16 + lr;
                v8bf kb = *(const v8bf*)(Kc + key * 128 +
                                         ((f * 64 + lg * 16) ^ ((key & 7) << 4)));
                sc[0][sub] = __builtin_amdgcn_mfma_f32_16x16x32_bf16(kb, qa[0][f], sc[0][sub], 0, 0, 0);
                sc[1][sub] = __builtin_amdgcn_mfma_f32_16x16x32_bf16(kb, qa[1][f], sc[1][sub], 0, 0, 0);
            }
        }
        __builtin_amdgcn_s_setprio(0);

        // ---- native exp2 + hw packed bf16 convert ----
        uint pk[2][8];
        #pragma unroll
        for (int st = 0; st < 2; ++st) {
            #pragma unroll
            for (int sub = 0; sub < 4; ++sub) {
                float p0 = __builtin_amdgcn_exp2f(sc[st][sub][0]);
                float p1 = __builtin_amdgcn_exp2f(sc[st][sub][1]);
                float p2 = __builtin_amdgcn_exp2f(sc[st][sub][2]);
                float p3 = __builtin_amdgcn_exp2f(sc[st][sub][3]);
                pk[st][sub * 2 + 0] = cvt_pk_bf16(p0, p1);
                pk[st][sub * 2 + 1] = cvt_pk_bf16(p2, p3);
            }
        }

        // ---- PV + den-MFMA: V fragments shared by both strips ----
        __builtin_amdgcn_s_setprio(1);
        #pragma unroll
        for (int f = 0; f < 2; ++f) {
            union { uint u[4]; v8bf v; } pa0, pa1;
            #pragma unroll
            for (int j = 0; j < 4; ++j) { pa0.u[j] = pk[0][4 * f + j]; pa1.u[j] = pk[1][4 * f + j]; }
            den4[0] = __builtin_amdgcn_mfma_f32_16x16x32_bf16(pa0.v, ones.v, den4[0], 0, 0, 0);
            den4[1] = __builtin_amdgcn_mfma_f32_16x16x32_bf16(pa1.v, ones.v, den4[1], 0, 0, 0);
            #pragma unroll
            for (int sub = 0; sub < 4; ++sub) {
                int dk = sub * 16 + lr;
                v8bf vb = *(const v8bf*)(Vc + dk * 128 +
                                         ((f * 64 + lg * 16) ^ ((dk & 7) << 4)));
                o[0][sub] = __builtin_amdgcn_mfma_f32_16x16x32_bf16(pa0.v, vb, o[0][sub], 0, 0, 0);
                o[1][sub] = __builtin_amdgcn_mfma_f32_16x16x32_bf16(pa1.v, vb, o[1][sub], 0, 0, 0);
            }
        }
        __builtin_amdgcn_s_setprio(0);
    };

    // ---- 4-deep ring, counted vmcnt: stages t+1,t+2 in flight across barriers
    STAGE_KV(0, 0);
    STAGE_KV(1, 1);
    STAGE_KV(2, 2);

    for (int tb = 0; tb < 28; tb += 4) {
        #pragma unroll
        for (int i = 0; i < 4; ++i) {
            asm volatile("s_waitcnt vmcnt(4)" ::: "memory");  // oldest stage landed
            RAW_BARRIER();
            STAGE_KV((i + 3) & 3, tb + i + 3);  // refill just-freed buffer
            compute(i);
        }
    }
    // t=28: last stage issue (stage 31 -> buf 3), compute buf 0
    asm volatile("s_waitcnt vmcnt(4)" ::: "memory");
    RAW_BARRIER();
    STAGE_KV(3, 31);
    compute(0);
    // t=29..31: drain tail
    asm volatile("s_waitcnt vmcnt(4)" ::: "memory");
    RAW_BARRIER();
    compute(1);
    asm volatile("s_waitcnt vmcnt(2)" ::: "memory");
    RAW_BARRIER();
    compute(2);
    asm volatile("s_waitcnt vmcnt(0)" ::: "memory");
    RAW_BARRIER();
    compute(3);

    // den4[st][reg] = den for q-row 4*lg+reg (all 16 cols identical)
    #pragma unroll
    for (int st = 0; st < 2; ++st) {
        size_t obase = (size_t)b * SEQ * D_MODEL +
                       (size_t)(qx * 256 + w * 32 + st * 16 + lg * 4) * D_MODEL + h * DKH;
        #pragma unroll
        for (int reg = 0; reg < 4; ++reg) {
            float inv = 1.f / den4[st][reg];
            #pragma unroll
            for (int sub = 0; sub < 4; ++sub)
                Out[obase + (size_t)reg * D_MODEL + sub * 16 + lr] = o[st][sub][reg] * inv;
        }
    }
#undef STAGE_KV
}

extern "C" void kernel_launch(void* const* d_in, const int* in_sizes, int n_in,
                              void* d_out, int out_size, void* d_ws, size_t ws_size,
                              hipStream_t stream) {
    const float* x   = (const float*)d_in[0];
    const float* z_q = (const float*)d_in[1];
    const float* b_q = (const float*)d_in[2];
    const float* z_k = (const float*)d_in[3];
    const float* b_k = (const float*)d_in[4];
    const float* w_v = (const float*)d_in[5];
    const float* b_v = (const float*)d_in[6];
    float* out = (float*)d_out;

    // ws (~70MB): Pq bf16 16MB | xb 16MB (Qb aliases after GEMM) | Wcat 6MB
    //           | VT 16MB | Kb 16MB | aux.   Pk bf16 lives in d_out (scratch).
    ushort* Pq   = (ushort*)d_ws;
    ushort* xb   = Pq + NELEM;
    ushort* Qb   = xb;                               // alias: xb dead after GEMM
    ushort* Wcat = xb + NELEM;                       // [3072][1024] bf16
    ushort* VT   = Wcat + (size_t)3 * D_MODEL * D_MODEL;
    ushort* Kb   = VT + NELEM;
    float*  aux  = (float*)(Kb + NELEM);
    float*  lam  = aux + 6144;                       // 8192 floats
    ushort* Pk   = (ushort*)out;                     // d_out as scratch

    // ALL input prep in one launch (x-cast+lam, zq/zk transpose-cast, wv cast,
    // per-column Poincare constants)
    mega_prep<<<dim3(11264), 256, 0, stream>>>(x, z_q, b_q, z_k, b_k, w_v,
                                               xb, lam, Wcat, aux);

    // One fused GEMM: Q-chunk -> Pq, K-chunk -> Pk (d_out), V-chunk -> VT
    gemm_fused<<<dim3(1536), 256, 0, stream>>>(xb, Wcat, b_v, Pq, Pk, VT);

    // Fused Poincare epilogues: y=0 Q chain (scale log2e/8), y=1 K chain
    poincare_epilogue2<<<dim3(NTOK, 2), 256, 0, stream>>>(Pq, Pk, lam, aux, Qb, Kb);

    attn_mfma<<<dim3(512), 512, 0, stream>>>(Qb, Kb, VT, out);
}

// Round 18
// 166.106 us; speedup vs baseline: 1.0052x; 1.0052x over previous
//
#include <hip/hip_runtime.h>
#include <hip/hip_bf16.h>
#include <math.h>

#define D_MODEL 1024
#define NHEADS  16
#define DKH     64
#define BATCH   4
#define SEQ     2048
#define NTOK    (BATCH * SEQ)   // 8192
#define NELEM   ((size_t)NTOK * D_MODEL)  // 8388608

typedef __bf16 v8bf __attribute__((ext_vector_type(8)));
typedef float  v4f  __attribute__((ext_vector_type(4)));

__device__ __forceinline__ v8bf ld_bf16x8(const ushort* p) {
    union { uint4 u; v8bf b; } cv;
    cv.u = *(const uint4*)p;
    return cv.b;
}
__device__ __forceinline__ ushort f2bf(float f) {
    __hip_bfloat16 h = __float2bfloat16(f);
    return *(ushort*)&h;
}
// hardware packed f32x2 -> bf16x2 (RNE), single VALU op
__device__ __forceinline__ uint cvt_pk_bf16(float lo, float hi) {
    uint r;
    asm("v_cvt_pk_bf16_f32 %0, %1, %2" : "=v"(r) : "v"(lo), "v"(hi));
    return r;
}

#define GLOAD_LDS16(gsrc, ldst)                                            \
    __builtin_amdgcn_global_load_lds(                                      \
        (const __attribute__((address_space(1))) void*)(gsrc),             \
        (__attribute__((address_space(3))) void*)(ldst), 16, 0, 0)

#define RAW_BARRIER() __builtin_amdgcn_s_barrier()

// ---------------- block reduce (256 threads = 4 waves) ----------------
__device__ __forceinline__ float block_reduce_sum(float v, float* sbuf) {
    #pragma unroll
    for (int off = 32; off > 0; off >>= 1)
        v += __shfl_xor(v, off, 64);
    int lane = threadIdx.x & 63;
    int wid  = threadIdx.x >> 6;
    if (lane == 0) sbuf[wid] = v;
    __syncthreads();
    float total = sbuf[0] + sbuf[1] + sbuf[2] + sbuf[3];
    __syncthreads();
    return total;
}

// ---------------- mega prep: all input prep in ONE launch --------------------
// blocks [0,8192):      x -> bf16 cast + per-row lam = 2/(1-|x|^2)
// blocks [8192,8704):   zq/zk transpose-cast into Wcat rows [0,2048)
// blocks [8704,9216):   w_v cast into Wcat rows [2048,3072)
// blocks [9216,11264):  per-column constants c1/sh/tz for q and k chains
__global__ __launch_bounds__(256) void mega_prep(const float* __restrict__ x,
                                                 const float* __restrict__ z_q,
                                                 const float* __restrict__ r_q,
                                                 const float* __restrict__ z_k,
                                                 const float* __restrict__ r_k,
                                                 const float* __restrict__ w_v,
                                                 ushort* __restrict__ xb,
                                                 float* __restrict__ lam,
                                                 ushort* __restrict__ Wcat,
                                                 float* __restrict__ aux) {
    __shared__ float tile[64][65];
    __shared__ float sbuf[4];
    int bid = blockIdx.x;
    int t = threadIdx.x;

    if (bid < 8192) {
        // ---- cast_x_lam ----
        int n = bid;
        const float* xr = x + (size_t)n * D_MODEL;
        float4 v = *(const float4*)&xr[t * 4];
        float s = v.x * v.x + v.y * v.y + v.z * v.z + v.w * v.w;
        float xn2 = block_reduce_sum(s, sbuf);
        if (t == 0) lam[n] = 2.f / (1.f - xn2);
        ushort u[4] = {f2bf(v.x), f2bf(v.y), f2bf(v.z), f2bf(v.w)};
        *(uint2*)&xb[(size_t)n * D_MODEL + t * 4] = *(uint2*)u;
    } else if (bid < 8704) {
        // ---- cast_transpose: zT[m][k] = z[k][m] ----
        int idx = bid - 8192;
        int zsel = idx >> 8;
        int rem = idx & 255;
        int m0 = (rem & 15) * 64, k0 = (rem >> 4) * 64;
        const float* z = zsel ? z_k : z_q;
        ushort* zT = Wcat + (size_t)zsel * D_MODEL * D_MODEL;
        #pragma unroll
        for (int i = 0; i < 4; ++i) {
            int r = (t >> 4) + 16 * i;
            int c = (t & 15) * 4;
            float4 v = *(const float4*)&z[(size_t)(k0 + r) * D_MODEL + m0 + c];
            tile[r][c + 0] = v.x; tile[r][c + 1] = v.y;
            tile[r][c + 2] = v.z; tile[r][c + 3] = v.w;
        }
        __syncthreads();
        #pragma unroll
        for (int i = 0; i < 2; ++i) {
            int idx2 = t + 256 * i;
            int r = idx2 >> 3;
            int c8 = idx2 & 7;
            ushort u[8];
            #pragma unroll
            for (int j = 0; j < 8; ++j)
                u[j] = f2bf(tile[c8 * 8 + j][r]);
            *(uint4*)&zT[(size_t)(m0 + r) * D_MODEL + k0 + c8 * 8] = *(uint4*)u;
        }
    } else if (bid < 9216) {
        // ---- cast_bf16 of w_v into Wcat rows [2048,3072) ----
        size_t i = ((size_t)(bid - 8704) * 256 + t) * 8;
        float4 a = *(const float4*)(w_v + i);
        float4 b = *(const float4*)(w_v + i + 4);
        ushort u[8] = {f2bf(a.x), f2bf(a.y), f2bf(a.z), f2bf(a.w),
                       f2bf(b.x), f2bf(b.y), f2bf(b.z), f2bf(b.w)};
        *(uint4*)(Wcat + (size_t)2 * D_MODEL * D_MODEL + i) = *(uint4*)u;
    } else {
        // ---- prep: c1 = cosh(2r)/||z_col||, sh = sinh(2r), tz = 2*||z_col|| ----
        int idx = bid - 9216;
        int which = idx >> 10;
        int m = idx & 1023;
        const float* z = which ? z_k : z_q;
        const float* r = which ? r_k : r_q;
        float* base = aux + which * 3072;
        float s = 0.f;
        for (int k = t; k < D_MODEL; k += 256) {
            float zv = z[k * D_MODEL + m];
            s += zv * zv;
        }
        float tot = block_reduce_sum(s, sbuf);
        if (t == 0) {
            float n = fmaxf(sqrtf(tot), 1e-15f);
            float tc = 2.f * r[m];   // c_sqrt = 1
            base[m]        = coshf(tc) / n;
            base[1024 + m] = sinhf(tc);
            base[2048 + m] = 2.f * n;
        }
    }
}

// ---------------- fused bf16 MFMA GEMM: C[8192,3072] = xb @ Wcat^T ------------
// R13 ring + NEW wave mapping: per-wave output 128x32 (1M x 4N). B-fragments
// are reused across the full M extent -> 20 LDS reads per K-step (vs 32),
// cutting per-CU LDS read traffic 128->80 KB/K-step (was the binding pipe).
// 128x128 tile, BK=64, 2-buffer LDS ring + counted vmcnt + RAW barriers +
// both-sides XOR swizzle (0 conflicts measured).
// Chunk 0 -> bf16 Pq, chunk 1 -> bf16 Pk (d_out scratch), chunk 2 -> bf16 VT.
__global__ __launch_bounds__(256) void gemm_fused(const ushort* __restrict__ A,
                                                  const ushort* __restrict__ W,
                                                  const float* __restrict__ bias,
                                                  ushort* __restrict__ Pq,
                                                  ushort* __restrict__ Pk,
                                                  ushort* __restrict__ VT) {
    const int K = 1024;
    __shared__ ushort As[2][128][64];   // 32KB
    __shared__ ushort Bs[2][128][64];   // 32KB
    int tid = threadIdx.x;
    int w = tid >> 6, l = tid & 63;
    int lr = l & 15, lg = l >> 4;
    // XCD swizzle + L2 window: per XCD, groups of 32 t cover 8 M-tiles x 4 N-tiles
    int bid = blockIdx.x;
    int xcd = bid & 7, t = bid >> 3;                 // t in 0..191
    int m0 = (xcd * 8 + ((t >> 2) & 7)) * 128;
    int n0 = ((t >> 5) * 4 + (t & 3)) * 128;

    v4f acc[8][2];
    #pragma unroll
    for (int i = 0; i < 8; ++i)
        #pragma unroll
        for (int j = 0; j < 2; ++j)
            acc[i][j] = (v4f){0.f, 0.f, 0.f, 0.f};

    int srow = w * 32 + (l >> 3);
    // pre-swizzled source chunk: LDS row r holds chunk c at position c ^ (r&7)
    int scol = ((l & 7) ^ ((l >> 3) & 7)) * 8;

#define STAGE_G(buf, k0) do {                                                 \
        _Pragma("unroll")                                                     \
        for (int j = 0; j < 4; ++j) {                                         \
            GLOAD_LDS16(A + (size_t)(m0 + srow + j * 8) * K + (k0) + scol,    \
                        &As[buf][w * 32 + j * 8][0]);                         \
            GLOAD_LDS16(W + (size_t)(n0 + srow + j * 8) * K + (k0) + scol,    \
                        &Bs[buf][w * 32 + j * 8][0]);                         \
        }                                                                     \
    } while (0)

    int swz = (lr & 7) << 4;   // read-side XOR (row&7 == lr&7 for all fragments)

    STAGE_G(0, 0);
    for (int k0 = 0; k0 < K; k0 += 64) {
        int cur = (k0 >> 6) & 1;
        if (k0 + 64 < K) {
            STAGE_G(cur ^ 1, k0 + 64);                    // 8 loads in flight
            asm volatile("s_waitcnt vmcnt(8)" ::: "memory");  // cur's landed
        } else {
            asm volatile("s_waitcnt vmcnt(0)" ::: "memory");
        }
        RAW_BARRIER();
        #pragma unroll
        for (int kk = 0; kk < 2; ++kk) {
            v8bf av[8], bv[2];
            #pragma unroll
            for (int i = 0; i < 8; ++i)
                av[i] = *(const v8bf*)((const char*)&As[cur][i * 16 + lr][0]
                                       + ((kk * 64 + lg * 16) ^ swz));
            #pragma unroll
            for (int j = 0; j < 2; ++j)
                bv[j] = *(const v8bf*)((const char*)&Bs[cur][w * 32 + j * 16 + lr][0]
                                       + ((kk * 64 + lg * 16) ^ swz));
            #pragma unroll
            for (int i = 0; i < 8; ++i)
                #pragma unroll
                for (int j = 0; j < 2; ++j)
                    acc[i][j] = __builtin_amdgcn_mfma_f32_16x16x32_bf16(av[i], bv[j], acc[i][j], 0, 0, 0);
        }
        RAW_BARRIER();
    }
#undef STAGE_G

    int chunk = n0 >> 10;          // 0,1,2 (uniform per block)
    // D layout: lane holds col=lr, rows 4*lg+reg (reg 0..3 consecutive)
    #pragma unroll
    for (int i = 0; i < 8; ++i) {
        #pragma unroll
        for (int j = 0; j < 2; ++j) {
            int col = n0 + w * 32 + j * 16 + lr;
            int cl  = col & 1023;  // column within chunk
            if (chunk < 2) {
                ushort* P = chunk ? Pk : Pq;
                #pragma unroll
                for (int reg = 0; reg < 4; ++reg) {
                    int row = m0 + i * 16 + 4 * lg + reg;
                    P[(size_t)row * D_MODEL + cl] = f2bf(acc[i][j][reg]);
                }
            } else {
                float badd = bias[cl];
                int hh = cl >> 6, dk = cl & 63;
                int row = m0 + i * 16 + 4 * lg;   // 4 consecutive tokens
                int bb = row >> 11, ss = row & 2047;
                // attention key-permutation (bit shuffle, preserves low 2 bits)
                int sp = (ss & ~63) | (ss & 0x23) | ((ss & 0x0C) << 1) | ((ss & 0x10) >> 2);
                ushort u[4];
                #pragma unroll
                for (int reg = 0; reg < 4; ++reg)
                    u[reg] = f2bf(acc[i][j][reg] + badd);
                *(uint2*)&VT[(((size_t)(bb * NHEADS + hh)) * DKH + dk) * SEQ + sp] = *(uint2*)u;
            }
        }
    }
}

// ---------------- Poincare epilogue (fast-math closed form, bf16 P in) -------
__global__ __launch_bounds__(256) void poincare_epilogue2(const ushort* __restrict__ Pq,
                                                          const ushort* __restrict__ Pk,
                                                          const float* __restrict__ lam_,
                                                          const float* __restrict__ aux,
                                                          ushort* __restrict__ Qb,
                                                          ushort* __restrict__ Kb) {
    __shared__ float sbuf[4];
    int which = blockIdx.y;
    const ushort* P  = which ? Pk : Pq;
    ushort* outb     = which ? Kb : Qb;
    const float* c1_ = aux + which * 3072;
    const float* sh_ = c1_ + 1024;
    const float* tz_ = c1_ + 2048;
    float oscale = which ? 1.0f : 0.1803368801f;  // K: 1; Q: log2(e)/8

    int n = blockIdx.x;
    float lam = lam_[n];
    float lm1 = lam - 1.f;
    int o = threadIdx.x * 4;
    uint2 pu = *(const uint2*)&P[(size_t)n * D_MODEL + o];
    float4 c1 = *(const float4*)&c1_[o];
    float4 sh = *(const float4*)&sh_[o];
    float4 tz = *(const float4*)&tz_[o];
    float pv[4];
    pv[0] = __uint_as_float(pu.x << 16);
    pv[1] = __uint_as_float(pu.x & 0xffff0000u);
    pv[2] = __uint_as_float(pu.y << 16);
    pv[3] = __uint_as_float(pu.y & 0xffff0000u);
    float c1v[4] = {c1.x, c1.y, c1.z, c1.w};
    float shv[4] = {sh.x, sh.y, sh.z, sh.w};
    float tzv[4] = {tz.x, tz.y, tz.z, tz.w};
    float w[4];
    float wn2 = 0.f;
    #pragma unroll
    for (int i = 0; i < 4; ++i) {
        float t  = fmaf(lam * c1v[i], pv[i], -lm1 * shv[i]);
        float at = fabsf(t);
        float u  = at + __builtin_amdgcn_sqrtf(fmaf(at, at, 1.f));
        float tl = tzv[i] * __builtin_amdgcn_logf(u);       // tz * log2(u)
        float e  = __builtin_amdgcn_exp2f(tl);
        float em = __builtin_amdgcn_exp2f(-tl);
        float wa = 0.5f * (e - em);
        w[i] = copysignf(wa, t);
        wn2 = fmaf(wa, wa, wn2);
    }
    wn2 = block_reduce_sum(wn2, sbuf);
    float invd = oscale / (1.f + __builtin_amdgcn_sqrtf(1.f + wn2));
    uint2 st;
    st.x = cvt_pk_bf16(w[0] * invd, w[1] * invd);
    st.y = cvt_pk_bf16(w[2] * invd, w[3] * invd);
    *(uint2*)&outb[(size_t)n * D_MODEL + o] = st;
}

// ---------------- MFMA attention (R9 structure + RAW barriers) ---------------
// 8 waves x 2 strips = 256 q/block, 512 blocks. P stays in registers
// (V key-permuted in global). den via MFMA vs ones. exp2 native.
// 4-deep LDS ring + counted vmcnt; raw s_barrier so prefetch STAYS in flight.
__global__ __launch_bounds__(512, 4) void attn_mfma(const ushort* __restrict__ Qb,
                                                    const ushort* __restrict__ Kb,
                                                    const ushort* __restrict__ VT,
                                                    float* __restrict__ Out) {
    __shared__ ushort Klds[4][64 * 64];   // [key][dk], chunk pos = c8 ^ (key&7)
    __shared__ ushort Vlds[4][64 * 64];   // [dk][keypos], chunk pos = c8 ^ (dk&7)

    int tid = threadIdx.x;
    int w = tid >> 6, l = tid & 63;
    int lr = l & 15, lg = l >> 4;

    // XCD swizzle: 512 blocks; xcd = flat&7 owns 8 (b,h) groups x 8 q-tiles
    int flat = blockIdx.x;
    int low3 = flat & 7;
    int rest = flat >> 3;            // 0..63
    int qx   = rest & 7;             // q-tile 0..7 (256 rows each)
    int g    = (rest & ~7) | low3;   // (b,h) 0..63
    int h = g & 15, b = g >> 4;

    const ushort* Kh = Kb + (size_t)b * SEQ * D_MODEL + h * DKH;
    const ushort* Vh = VT + (size_t)(b * NHEADS + h) * DKH * SEQ;

    // Q fragments for 2 strips (scale log2e/8 folded at epilogue); q = lr
    const ushort* qp0 = Qb + (size_t)b * SEQ * D_MODEL + h * DKH
                      + (size_t)(qx * 256 + w * 32 + lr) * D_MODEL;
    const ushort* qp1 = qp0 + (size_t)16 * D_MODEL;
    v8bf qa[2][2];
    qa[0][0] = ld_bf16x8(qp0 + lg * 8);
    qa[0][1] = ld_bf16x8(qp0 + 32 + lg * 8);
    qa[1][0] = ld_bf16x8(qp1 + lg * 8);
    qa[1][1] = ld_bf16x8(qp1 + 32 + lg * 8);

    // staging: 1 K-DMA + 1 V-DMA per thread per stage, pre-swizzled source
    int row = tid >> 3;                       // 0..63
    int c8  = (tid & 7) ^ (row & 7);
    const ushort* kg = Kh + (size_t)row * D_MODEL + c8 * 8;
    const ushort* vg = Vh + (size_t)row * SEQ + c8 * 8;

#define STAGE_KV(buf, st)  do {                                              \
        GLOAD_LDS16(kg + (size_t)(st) * 64 * D_MODEL, &Klds[buf][tid * 8]);  \
        GLOAD_LDS16(vg + (st) * 64, &Vlds[buf][tid * 8]);                    \
    } while (0)

    v4f o[2][4];
    v4f den4[2];
    #pragma unroll
    for (int st = 0; st < 2; ++st) {
        den4[st] = (v4f){0.f, 0.f, 0.f, 0.f};
        #pragma unroll
        for (int i = 0; i < 4; ++i) o[st][i] = (v4f){0.f, 0.f, 0.f, 0.f};
    }
    union { uint u[4]; v8bf v; } ones;
    ones.u[0] = ones.u[1] = ones.u[2] = ones.u[3] = 0x3f803f80u;

    auto compute = [&](int buf) {
        const char* Kc = (const char*)&Klds[buf][0];
        const char* Vc = (const char*)&Vlds[buf][0];

        // ---- QK^T swapped, both strips share each K fragment ----
        v4f sc[2][4];
        #pragma unroll
        for (int st = 0; st < 2; ++st)
            #pragma unroll
            for (int i = 0; i < 4; ++i) sc[st][i] = (v4f){0.f, 0.f, 0.f, 0.f};
        __builtin_amdgcn_s_setprio(1);
        #pragma unroll
        for (int f = 0; f < 2; ++f) {
            #pragma unroll
            for (int sub = 0; sub < 4; ++sub) {
                int key = sub * 16 + lr;
                v8bf kb = *(const v8bf*)(Kc + key * 128 +
                                         ((f * 64 + lg * 16) ^ ((key & 7) << 4)));
                sc[0][sub] = __builtin_amdgcn_mfma_f32_16x16x32_bf16(kb, qa[0][f], sc[0][sub], 0, 0, 0);
                sc[1][sub] = __builtin_amdgcn_mfma_f32_16x16x32_bf16(kb, qa[1][f], sc[1][sub], 0, 0, 0);
            }
        }
        __builtin_amdgcn_s_setprio(0);

        // ---- native exp2 + hw packed bf16 convert ----
        uint pk[2][8];
        #pragma unroll
        for (int st = 0; st < 2; ++st) {
            #pragma unroll
            for (int sub = 0; sub < 4; ++sub) {
                float p0 = __builtin_amdgcn_exp2f(sc[st][sub][0]);
                float p1 = __builtin_amdgcn_exp2f(sc[st][sub][1]);
                float p2 = __builtin_amdgcn_exp2f(sc[st][sub][2]);
                float p3 = __builtin_amdgcn_exp2f(sc[st][sub][3]);
                pk[st][sub * 2 + 0] = cvt_pk_bf16(p0, p1);
                pk[st][sub * 2 + 1] = cvt_pk_bf16(p2, p3);
            }
        }

        // ---- PV + den-MFMA: V fragments shared by both strips ----
        __builtin_amdgcn_s_setprio(1);
        #pragma unroll
        for (int f = 0; f < 2; ++f) {
            union { uint u[4]; v8bf v; } pa0, pa1;
            #pragma unroll
            for (int j = 0; j < 4; ++j) { pa0.u[j] = pk[0][4 * f + j]; pa1.u[j] = pk[1][4 * f + j]; }
            den4[0] = __builtin_amdgcn_mfma_f32_16x16x32_bf16(pa0.v, ones.v, den4[0], 0, 0, 0);
            den4[1] = __builtin_amdgcn_mfma_f32_16x16x32_bf16(pa1.v, ones.v, den4[1], 0, 0, 0);
            #pragma unroll
            for (int sub = 0; sub < 4; ++sub) {
                int dk = sub * 16 + lr;
                v8bf vb = *(const v8bf*)(Vc + dk * 128 +
                                         ((f * 64 + lg * 16) ^ ((dk & 7) << 4)));
                o[0][sub] = __builtin_amdgcn_mfma_f32_16x16x32_bf16(pa0.v, vb, o[0][sub], 0, 0, 0);
                o[1][sub] = __builtin_amdgcn_mfma_f32_16x16x32_bf16(pa1.v, vb, o[1][sub], 0, 0, 0);
            }
        }
        __builtin_amdgcn_s_setprio(0);
    };

    // ---- 4-deep ring, counted vmcnt: stages t+1,t+2 in flight across barriers
    STAGE_KV(0, 0);
    STAGE_KV(1, 1);
    STAGE_KV(2, 2);

    for (int tb = 0; tb < 28; tb += 4) {
        #pragma unroll
        for (int i = 0; i < 4; ++i) {
            asm volatile("s_waitcnt vmcnt(4)" ::: "memory");  // oldest stage landed
            RAW_BARRIER();
            STAGE_KV((i + 3) & 3, tb + i + 3);  // refill just-freed buffer
            compute(i);
        }
    }
    // t=28: last stage issue (stage 31 -> buf 3), compute buf 0
    asm volatile("s_waitcnt vmcnt(4)" ::: "memory");
    RAW_BARRIER();
    STAGE_KV(3, 31);
    compute(0);
    // t=29..31: drain tail
    asm volatile("s_waitcnt vmcnt(4)" ::: "memory");
    RAW_BARRIER();
    compute(1);
    asm volatile("s_waitcnt vmcnt(2)" ::: "memory");
    RAW_BARRIER();
    compute(2);
    asm volatile("s_waitcnt vmcnt(0)" ::: "memory");
    RAW_BARRIER();
    compute(3);

    // den4[st][reg] = den for q-row 4*lg+reg (all 16 cols identical)
    #pragma unroll
    for (int st = 0; st < 2; ++st) {
        size_t obase = (size_t)b * SEQ * D_MODEL +
                       (size_t)(qx * 256 + w * 32 + st * 16 + lg * 4) * D_MODEL + h * DKH;
        #pragma unroll
        for (int reg = 0; reg < 4; ++reg) {
            float inv = 1.f / den4[st][reg];
            #pragma unroll
            for (int sub = 0; sub < 4; ++sub)
                Out[obase + (size_t)reg * D_MODEL + sub * 16 + lr] = o[st][sub][reg] * inv;
        }
    }
#undef STAGE_KV
}

extern "C" void kernel_launch(void* const* d_in, const int* in_sizes, int n_in,
                              void* d_out, int out_size, void* d_ws, size_t ws_size,
                              hipStream_t stream) {
    const float* x   = (const float*)d_in[0];
    const float* z_q = (const float*)d_in[1];
    const float* b_q = (const float*)d_in[2];
    const float* z_k = (const float*)d_in[3];
    const float* b_k = (const float*)d_in[4];
    const float* w_v = (const float*)d_in[5];
    const float* b_v = (const float*)d_in[6];
    float* out = (float*)d_out;

    // ws (~70MB): Pq bf16 16MB | xb 16MB (Qb aliases after GEMM) | Wcat 6MB
    //           | VT 16MB | Kb 16MB | aux.   Pk bf16 lives in d_out (scratch).
    ushort* Pq   = (ushort*)d_ws;
    ushort* xb   = Pq + NELEM;
    ushort* Qb   = xb;                               // alias: xb dead after GEMM
    ushort* Wcat = xb + NELEM;                       // [3072][1024] bf16
    ushort* VT   = Wcat + (size_t)3 * D_MODEL * D_MODEL;
    ushort* Kb   = VT + NELEM;
    float*  aux  = (float*)(Kb + NELEM);
    float*  lam  = aux + 6144;                       // 8192 floats
    ushort* Pk   = (ushort*)out;                     // d_out as scratch

    // ALL input prep in one launch (x-cast+lam, zq/zk transpose-cast, wv cast,
    // per-column Poincare constants)
    mega_prep<<<dim3(11264), 256, 0, stream>>>(x, z_q, b_q, z_k, b_k, w_v,
                                               xb, lam, Wcat, aux);

    // One fused GEMM: Q-chunk -> Pq, K-chunk -> Pk (d_out), V-chunk -> VT
    gemm_fused<<<dim3(1536), 256, 0, stream>>>(xb, Wcat, b_v, Pq, Pk, VT);

    // Fused Poincare epilogues: y=0 Q chain (scale log2e/8), y=1 K chain
    poincare_epilogue2<<<dim3(NTOK, 2), 256, 0, stream>>>(Pq, Pk, lam, aux, Qb, Kb);

    attn_mfma<<<dim3(512), 512, 0, stream>>>(Qb, Kb, VT, out);
}

// Round 19
// 159.906 us; speedup vs baseline: 1.0442x; 1.0388x over previous
//
#include <hip/hip_runtime.h>
#include <hip/hip_bf16.h>
#include <math.h>

#define D_MODEL 1024
#define NHEADS  16
#define DKH     64
#define BATCH   4
#define SEQ     2048
#define NTOK    (BATCH * SEQ)   // 8192
#define NELEM   ((size_t)NTOK * D_MODEL)  // 8388608

typedef __bf16 v8bf __attribute__((ext_vector_type(8)));
typedef float  v4f  __attribute__((ext_vector_type(4)));

__device__ __forceinline__ v8bf ld_bf16x8(const ushort* p) {
    union { uint4 u; v8bf b; } cv;
    cv.u = *(const uint4*)p;
    return cv.b;
}
__device__ __forceinline__ ushort f2bf(float f) {
    __hip_bfloat16 h = __float2bfloat16(f);
    return *(ushort*)&h;
}
// hardware packed f32x2 -> bf16x2 (RNE), single VALU op
__device__ __forceinline__ uint cvt_pk_bf16(float lo, float hi) {
    uint r;
    asm("v_cvt_pk_bf16_f32 %0, %1, %2" : "=v"(r) : "v"(lo), "v"(hi));
    return r;
}

#define GLOAD_LDS16(gsrc, ldst)                                            \
    __builtin_amdgcn_global_load_lds(                                      \
        (const __attribute__((address_space(1))) void*)(gsrc),             \
        (__attribute__((address_space(3))) void*)(ldst), 16, 0, 0)

#define RAW_BARRIER() __builtin_amdgcn_s_barrier()

// ---------------- block reduce (256 threads = 4 waves) ----------------
__device__ __forceinline__ float block_reduce_sum(float v, float* sbuf) {
    #pragma unroll
    for (int off = 32; off > 0; off >>= 1)
        v += __shfl_xor(v, off, 64);
    int lane = threadIdx.x & 63;
    int wid  = threadIdx.x >> 6;
    if (lane == 0) sbuf[wid] = v;
    __syncthreads();
    float total = sbuf[0] + sbuf[1] + sbuf[2] + sbuf[3];
    __syncthreads();
    return total;
}

// ---------------- mega prep: all input prep in ONE launch --------------------
// blocks [0,8192):     x -> bf16 cast + per-row lam = 2/(1-|x|^2)
// blocks [8192,8704):  zq/zk transpose-cast into Wcat rows [0,2048)
// blocks [8704,9216):  w_v cast into Wcat rows [2048,3072)
// blocks [9216,9280):  per-column constants c1/sh/tz for q,k (COALESCED:
//                      32 cols/block; half-wave reads 32 consecutive floats)
__global__ __launch_bounds__(256) void mega_prep(const float* __restrict__ x,
                                                 const float* __restrict__ z_q,
                                                 const float* __restrict__ r_q,
                                                 const float* __restrict__ z_k,
                                                 const float* __restrict__ r_k,
                                                 const float* __restrict__ w_v,
                                                 ushort* __restrict__ xb,
                                                 float* __restrict__ lam,
                                                 ushort* __restrict__ Wcat,
                                                 float* __restrict__ aux) {
    __shared__ float tile[64][65];
    __shared__ float sbuf[4];
    int bid = blockIdx.x;
    int t = threadIdx.x;

    if (bid < 8192) {
        // ---- cast_x_lam ----
        int n = bid;
        const float* xr = x + (size_t)n * D_MODEL;
        float4 v = *(const float4*)&xr[t * 4];
        float s = v.x * v.x + v.y * v.y + v.z * v.z + v.w * v.w;
        float xn2 = block_reduce_sum(s, sbuf);
        if (t == 0) lam[n] = 2.f / (1.f - xn2);
        ushort u[4] = {f2bf(v.x), f2bf(v.y), f2bf(v.z), f2bf(v.w)};
        *(uint2*)&xb[(size_t)n * D_MODEL + t * 4] = *(uint2*)u;
    } else if (bid < 8704) {
        // ---- cast_transpose: zT[m][k] = z[k][m] ----
        int idx = bid - 8192;
        int zsel = idx >> 8;
        int rem = idx & 255;
        int m0 = (rem & 15) * 64, k0 = (rem >> 4) * 64;
        const float* z = zsel ? z_k : z_q;
        ushort* zT = Wcat + (size_t)zsel * D_MODEL * D_MODEL;
        #pragma unroll
        for (int i = 0; i < 4; ++i) {
            int r = (t >> 4) + 16 * i;
            int c = (t & 15) * 4;
            float4 v = *(const float4*)&z[(size_t)(k0 + r) * D_MODEL + m0 + c];
            tile[r][c + 0] = v.x; tile[r][c + 1] = v.y;
            tile[r][c + 2] = v.z; tile[r][c + 3] = v.w;
        }
        __syncthreads();
        #pragma unroll
        for (int i = 0; i < 2; ++i) {
            int idx2 = t + 256 * i;
            int r = idx2 >> 3;
            int c8 = idx2 & 7;
            ushort u[8];
            #pragma unroll
            for (int j = 0; j < 8; ++j)
                u[j] = f2bf(tile[c8 * 8 + j][r]);
            *(uint4*)&zT[(size_t)(m0 + r) * D_MODEL + k0 + c8 * 8] = *(uint4*)u;
        }
    } else if (bid < 9216) {
        // ---- cast_bf16 of w_v into Wcat rows [2048,3072) ----
        size_t i = ((size_t)(bid - 8704) * 256 + t) * 8;
        float4 a = *(const float4*)(w_v + i);
        float4 b = *(const float4*)(w_v + i + 4);
        ushort u[8] = {f2bf(a.x), f2bf(a.y), f2bf(a.z), f2bf(a.w),
                       f2bf(b.x), f2bf(b.y), f2bf(b.z), f2bf(b.w)};
        *(uint4*)(Wcat + (size_t)2 * D_MODEL * D_MODEL + i) = *(uint4*)u;
    } else {
        // ---- prep constants, coalesced: block owns 32 columns of one z ----
        // thread t: column m = m0 + (t&31), rows k = (t>>5) + 8*j  (j=0..127).
        // Each 32-lane half-wave reads 32 consecutive floats -> 128B segments.
        int idx = bid - 9216;                 // 0..63
        int which = idx >> 5;                 // 0: q, 1: k
        int m0 = (idx & 31) * 32;
        const float* z = which ? z_k : z_q;
        const float* r = which ? r_k : r_q;
        float* base = aux + which * 3072;
        int mloc = t & 31;
        int krow = t >> 5;                    // 0..7
        float s = 0.f;
        #pragma unroll 8
        for (int j = 0; j < 128; ++j) {
            float zv = z[(size_t)(krow + 8 * j) * D_MODEL + m0 + mloc];
            s = fmaf(zv, zv, s);
        }
        // reduce the 8 k-groups per column via LDS (reuse tile storage)
        float* red = &tile[0][0];             // 32*8 floats
        red[krow * 32 + mloc] = s;
        __syncthreads();
        if (t < 32) {
            float tot = 0.f;
            #pragma unroll
            for (int g = 0; g < 8; ++g) tot += red[g * 32 + t];
            int m = m0 + t;
            float n = fmaxf(sqrtf(tot), 1e-15f);
            float tc = 2.f * r[m];            // c_sqrt = 1
            base[m]        = coshf(tc) / n;
            base[1024 + m] = sinhf(tc);
            base[2048 + m] = 2.f * n;
        }
    }
}

// ---------------- fused bf16 MFMA GEMM: C[8192,3072] = xb @ Wcat^T ------------
// R13/R18 plateau structure: 128x128 tile, BK=64, 2-buffer LDS ring + counted
// vmcnt + RAW barriers + both-sides XOR swizzle (0 conflicts). Wave output
// 128x32 (1Mx4N, B-frag reuse).
// Chunk 0 -> bf16 Pq, chunk 1 -> bf16 Pk (d_out scratch), chunk 2 -> bf16 VT.
__global__ __launch_bounds__(256) void gemm_fused(const ushort* __restrict__ A,
                                                  const ushort* __restrict__ W,
                                                  const float* __restrict__ bias,
                                                  ushort* __restrict__ Pq,
                                                  ushort* __restrict__ Pk,
                                                  ushort* __restrict__ VT) {
    const int K = 1024;
    __shared__ ushort As[2][128][64];   // 32KB
    __shared__ ushort Bs[2][128][64];   // 32KB
    int tid = threadIdx.x;
    int w = tid >> 6, l = tid & 63;
    int lr = l & 15, lg = l >> 4;
    // XCD swizzle + L2 window: per XCD, groups of 32 t cover 8 M-tiles x 4 N-tiles
    int bid = blockIdx.x;
    int xcd = bid & 7, t = bid >> 3;                 // t in 0..191
    int m0 = (xcd * 8 + ((t >> 2) & 7)) * 128;
    int n0 = ((t >> 5) * 4 + (t & 3)) * 128;

    v4f acc[8][2];
    #pragma unroll
    for (int i = 0; i < 8; ++i)
        #pragma unroll
        for (int j = 0; j < 2; ++j)
            acc[i][j] = (v4f){0.f, 0.f, 0.f, 0.f};

    int srow = w * 32 + (l >> 3);
    // pre-swizzled source chunk: LDS row r holds chunk c at position c ^ (r&7)
    int scol = ((l & 7) ^ ((l >> 3) & 7)) * 8;

#define STAGE_G(buf, k0) do {                                                 \
        _Pragma("unroll")                                                     \
        for (int j = 0; j < 4; ++j) {                                         \
            GLOAD_LDS16(A + (size_t)(m0 + srow + j * 8) * K + (k0) + scol,    \
                        &As[buf][w * 32 + j * 8][0]);                         \
            GLOAD_LDS16(W + (size_t)(n0 + srow + j * 8) * K + (k0) + scol,    \
                        &Bs[buf][w * 32 + j * 8][0]);                         \
        }                                                                     \
    } while (0)

    int swz = (lr & 7) << 4;   // read-side XOR (row&7 == lr&7 for all fragments)

    STAGE_G(0, 0);
    for (int k0 = 0; k0 < K; k0 += 64) {
        int cur = (k0 >> 6) & 1;
        if (k0 + 64 < K) {
            STAGE_G(cur ^ 1, k0 + 64);                    // 8 loads in flight
            asm volatile("s_waitcnt vmcnt(8)" ::: "memory");  // cur's landed
        } else {
            asm volatile("s_waitcnt vmcnt(0)" ::: "memory");
        }
        RAW_BARRIER();
        #pragma unroll
        for (int kk = 0; kk < 2; ++kk) {
            v8bf av[8], bv[2];
            #pragma unroll
            for (int i = 0; i < 8; ++i)
                av[i] = *(const v8bf*)((const char*)&As[cur][i * 16 + lr][0]
                                       + ((kk * 64 + lg * 16) ^ swz));
            #pragma unroll
            for (int j = 0; j < 2; ++j)
                bv[j] = *(const v8bf*)((const char*)&Bs[cur][w * 32 + j * 16 + lr][0]
                                       + ((kk * 64 + lg * 16) ^ swz));
            #pragma unroll
            for (int i = 0; i < 8; ++i)
                #pragma unroll
                for (int j = 0; j < 2; ++j)
                    acc[i][j] = __builtin_amdgcn_mfma_f32_16x16x32_bf16(av[i], bv[j], acc[i][j], 0, 0, 0);
        }
        RAW_BARRIER();
    }
#undef STAGE_G

    int chunk = n0 >> 10;          // 0,1,2 (uniform per block)
    // D layout: lane holds col=lr, rows 4*lg+reg (reg 0..3 consecutive)
    #pragma unroll
    for (int i = 0; i < 8; ++i) {
        #pragma unroll
        for (int j = 0; j < 2; ++j) {
            int col = n0 + w * 32 + j * 16 + lr;
            int cl  = col & 1023;  // column within chunk
            if (chunk < 2) {
                ushort* P = chunk ? Pk : Pq;
                #pragma unroll
                for (int reg = 0; reg < 4; ++reg) {
                    int row = m0 + i * 16 + 4 * lg + reg;
                    P[(size_t)row * D_MODEL + cl] = f2bf(acc[i][j][reg]);
                }
            } else {
                float badd = bias[cl];
                int hh = cl >> 6, dk = cl & 63;
                int row = m0 + i * 16 + 4 * lg;   // 4 consecutive tokens
                int bb = row >> 11, ss = row & 2047;
                // attention key-permutation (bit shuffle, preserves low 2 bits)
                int sp = (ss & ~63) | (ss & 0x23) | ((ss & 0x0C) << 1) | ((ss & 0x10) >> 2);
                ushort u[4];
                #pragma unroll
                for (int reg = 0; reg < 4; ++reg)
                    u[reg] = f2bf(acc[i][j][reg] + badd);
                *(uint2*)&VT[(((size_t)(bb * NHEADS + hh)) * DKH + dk) * SEQ + sp] = *(uint2*)u;
            }
        }
    }
}

// ---------------- Poincare epilogue (fast-math closed form, bf16 P in) -------
__global__ __launch_bounds__(256) void poincare_epilogue2(const ushort* __restrict__ Pq,
                                                          const ushort* __restrict__ Pk,
                                                          const float* __restrict__ lam_,
                                                          const float* __restrict__ aux,
                                                          ushort* __restrict__ Qb,
                                                          ushort* __restrict__ Kb) {
    __shared__ float sbuf[4];
    int which = blockIdx.y;
    const ushort* P  = which ? Pk : Pq;
    ushort* outb     = which ? Kb : Qb;
    const float* c1_ = aux + which * 3072;
    const float* sh_ = c1_ + 1024;
    const float* tz_ = c1_ + 2048;
    float oscale = which ? 1.0f : 0.1803368801f;  // K: 1; Q: log2(e)/8

    int n = blockIdx.x;
    float lam = lam_[n];
    float lm1 = lam - 1.f;
    int o = threadIdx.x * 4;
    uint2 pu = *(const uint2*)&P[(size_t)n * D_MODEL + o];
    float4 c1 = *(const float4*)&c1_[o];
    float4 sh = *(const float4*)&sh_[o];
    float4 tz = *(const float4*)&tz_[o];
    float pv[4];
    pv[0] = __uint_as_float(pu.x << 16);
    pv[1] = __uint_as_float(pu.x & 0xffff0000u);
    pv[2] = __uint_as_float(pu.y << 16);
    pv[3] = __uint_as_float(pu.y & 0xffff0000u);
    float c1v[4] = {c1.x, c1.y, c1.z, c1.w};
    float shv[4] = {sh.x, sh.y, sh.z, sh.w};
    float tzv[4] = {tz.x, tz.y, tz.z, tz.w};
    float w[4];
    float wn2 = 0.f;
    #pragma unroll
    for (int i = 0; i < 4; ++i) {
        float t  = fmaf(lam * c1v[i], pv[i], -lm1 * shv[i]);
        float at = fabsf(t);
        float u  = at + __builtin_amdgcn_sqrtf(fmaf(at, at, 1.f));
        float tl = tzv[i] * __builtin_amdgcn_logf(u);       // tz * log2(u)
        float e  = __builtin_amdgcn_exp2f(tl);
        float em = __builtin_amdgcn_exp2f(-tl);
        float wa = 0.5f * (e - em);
        w[i] = copysignf(wa, t);
        wn2 = fmaf(wa, wa, wn2);
    }
    wn2 = block_reduce_sum(wn2, sbuf);
    float invd = oscale / (1.f + __builtin_amdgcn_sqrtf(1.f + wn2));
    uint2 st;
    st.x = cvt_pk_bf16(w[0] * invd, w[1] * invd);
    st.y = cvt_pk_bf16(w[2] * invd, w[3] * invd);
    *(uint2*)&outb[(size_t)n * D_MODEL + o] = st;
}

// ---------------- MFMA attention (R9 structure + RAW barriers) ---------------
// 8 waves x 2 strips = 256 q/block, 512 blocks. P stays in registers
// (V key-permuted in global). den via MFMA vs ones. exp2 native.
// 4-deep LDS ring + counted vmcnt; raw s_barrier so prefetch STAYS in flight.
__global__ __launch_bounds__(512, 4) void attn_mfma(const ushort* __restrict__ Qb,
                                                    const ushort* __restrict__ Kb,
                                                    const ushort* __restrict__ VT,
                                                    float* __restrict__ Out) {
    __shared__ ushort Klds[4][64 * 64];   // [key][dk], chunk pos = c8 ^ (key&7)
    __shared__ ushort Vlds[4][64 * 64];   // [dk][keypos], chunk pos = c8 ^ (dk&7)

    int tid = threadIdx.x;
    int w = tid >> 6, l = tid & 63;
    int lr = l & 15, lg = l >> 4;

    // XCD swizzle: 512 blocks; xcd = flat&7 owns 8 (b,h) groups x 8 q-tiles
    int flat = blockIdx.x;
    int low3 = flat & 7;
    int rest = flat >> 3;            // 0..63
    int qx   = rest & 7;             // q-tile 0..7 (256 rows each)
    int g    = (rest & ~7) | low3;   // (b,h) 0..63
    int h = g & 15, b = g >> 4;

    const ushort* Kh = Kb + (size_t)b * SEQ * D_MODEL + h * DKH;
    const ushort* Vh = VT + (size_t)(b * NHEADS + h) * DKH * SEQ;

    // Q fragments for 2 strips (scale log2e/8 folded at epilogue); q = lr
    const ushort* qp0 = Qb + (size_t)b * SEQ * D_MODEL + h * DKH
                      + (size_t)(qx * 256 + w * 32 + lr) * D_MODEL;
    const ushort* qp1 = qp0 + (size_t)16 * D_MODEL;
    v8bf qa[2][2];
    qa[0][0] = ld_bf16x8(qp0 + lg * 8);
    qa[0][1] = ld_bf16x8(qp0 + 32 + lg * 8);
    qa[1][0] = ld_bf16x8(qp1 + lg * 8);
    qa[1][1] = ld_bf16x8(qp1 + 32 + lg * 8);

    // staging: 1 K-DMA + 1 V-DMA per thread per stage, pre-swizzled source
    int row = tid >> 3;                       // 0..63
    int c8  = (tid & 7) ^ (row & 7);
    const ushort* kg = Kh + (size_t)row * D_MODEL + c8 * 8;
    const ushort* vg = Vh + (size_t)row * SEQ + c8 * 8;

#define STAGE_KV(buf, st)  do {                                              \
        GLOAD_LDS16(kg + (size_t)(st) * 64 * D_MODEL, &Klds[buf][tid * 8]);  \
        GLOAD_LDS16(vg + (st) * 64, &Vlds[buf][tid * 8]);                    \
    } while (0)

    v4f o[2][4];
    v4f den4[2];
    #pragma unroll
    for (int st = 0; st < 2; ++st) {
        den4[st] = (v4f){0.f, 0.f, 0.f, 0.f};
        #pragma unroll
        for (int i = 0; i < 4; ++i) o[st][i] = (v4f){0.f, 0.f, 0.f, 0.f};
    }
    union { uint u[4]; v8bf v; } ones;
    ones.u[0] = ones.u[1] = ones.u[2] = ones.u[3] = 0x3f803f80u;

    auto compute = [&](int buf) {
        const char* Kc = (const char*)&Klds[buf][0];
        const char* Vc = (const char*)&Vlds[buf][0];

        // ---- QK^T swapped, both strips share each K fragment ----
        v4f sc[2][4];
        #pragma unroll
        for (int st = 0; st < 2; ++st)
            #pragma unroll
            for (int i = 0; i < 4; ++i) sc[st][i] = (v4f){0.f, 0.f, 0.f, 0.f};
        __builtin_amdgcn_s_setprio(1);
        #pragma unroll
        for (int f = 0; f < 2; ++f) {
            #pragma unroll
            for (int sub = 0; sub < 4; ++sub) {
                int key = sub * 16 + lr;
                v8bf kb = *(const v8bf*)(Kc + key * 128 +
                                         ((f * 64 + lg * 16) ^ ((key & 7) << 4)));
                sc[0][sub] = __builtin_amdgcn_mfma_f32_16x16x32_bf16(kb, qa[0][f], sc[0][sub], 0, 0, 0);
                sc[1][sub] = __builtin_amdgcn_mfma_f32_16x16x32_bf16(kb, qa[1][f], sc[1][sub], 0, 0, 0);
            }
        }
        __builtin_amdgcn_s_setprio(0);

        // ---- native exp2 + hw packed bf16 convert ----
        uint pk[2][8];
        #pragma unroll
        for (int st = 0; st < 2; ++st) {
            #pragma unroll
            for (int sub = 0; sub < 4; ++sub) {
                float p0 = __builtin_amdgcn_exp2f(sc[st][sub][0]);
                float p1 = __builtin_amdgcn_exp2f(sc[st][sub][1]);
                float p2 = __builtin_amdgcn_exp2f(sc[st][sub][2]);
                float p3 = __builtin_amdgcn_exp2f(sc[st][sub][3]);
                pk[st][sub * 2 + 0] = cvt_pk_bf16(p0, p1);
                pk[st][sub * 2 + 1] = cvt_pk_bf16(p2, p3);
            }
        }

        // ---- PV + den-MFMA: V fragments shared by both strips ----
        __builtin_amdgcn_s_setprio(1);
        #pragma unroll
        for (int f = 0; f < 2; ++f) {
            union { uint u[4]; v8bf v; } pa0, pa1;
            #pragma unroll
            for (int j = 0; j < 4; ++j) { pa0.u[j] = pk[0][4 * f + j]; pa1.u[j] = pk[1][4 * f + j]; }
            den4[0] = __builtin_amdgcn_mfma_f32_16x16x32_bf16(pa0.v, ones.v, den4[0], 0, 0, 0);
            den4[1] = __builtin_amdgcn_mfma_f32_16x16x32_bf16(pa1.v, ones.v, den4[1], 0, 0, 0);
            #pragma unroll
            for (int sub = 0; sub < 4; ++sub) {
                int dk = sub * 16 + lr;
                v8bf vb = *(const v8bf*)(Vc + dk * 128 +
                                         ((f * 64 + lg * 16) ^ ((dk & 7) << 4)));
                o[0][sub] = __builtin_amdgcn_mfma_f32_16x16x32_bf16(pa0.v, vb, o[0][sub], 0, 0, 0);
                o[1][sub] = __builtin_amdgcn_mfma_f32_16x16x32_bf16(pa1.v, vb, o[1][sub], 0, 0, 0);
            }
        }
        __builtin_amdgcn_s_setprio(0);
    };

    // ---- 4-deep ring, counted vmcnt: stages t+1,t+2 in flight across barriers
    STAGE_KV(0, 0);
    STAGE_KV(1, 1);
    STAGE_KV(2, 2);

    for (int tb = 0; tb < 28; tb += 4) {
        #pragma unroll
        for (int i = 0; i < 4; ++i) {
            asm volatile("s_waitcnt vmcnt(4)" ::: "memory");  // oldest stage landed
            RAW_BARRIER();
            STAGE_KV((i + 3) & 3, tb + i + 3);  // refill just-freed buffer
            compute(i);
        }
    }
    // t=28: last stage issue (stage 31 -> buf 3), compute buf 0
    asm volatile("s_waitcnt vmcnt(4)" ::: "memory");
    RAW_BARRIER();
    STAGE_KV(3, 31);
    compute(0);
    // t=29..31: drain tail
    asm volatile("s_waitcnt vmcnt(4)" ::: "memory");
    RAW_BARRIER();
    compute(1);
    asm volatile("s_waitcnt vmcnt(2)" ::: "memory");
    RAW_BARRIER();
    compute(2);
    asm volatile("s_waitcnt vmcnt(0)" ::: "memory");
    RAW_BARRIER();
    compute(3);

    // den4[st][reg] = den for q-row 4*lg+reg (all 16 cols identical)
    #pragma unroll
    for (int st = 0; st < 2; ++st) {
        size_t obase = (size_t)b * SEQ * D_MODEL +
                       (size_t)(qx * 256 + w * 32 + st * 16 + lg * 4) * D_MODEL + h * DKH;
        #pragma unroll
        for (int reg = 0; reg < 4; ++reg) {
            float inv = 1.f / den4[st][reg];
            #pragma unroll
            for (int sub = 0; sub < 4; ++sub)
                Out[obase + (size_t)reg * D_MODEL + sub * 16 + lr] = o[st][sub][reg] * inv;
        }
    }
#undef STAGE_KV
}

extern "C" void kernel_launch(void* const* d_in, const int* in_sizes, int n_in,
                              void* d_out, int out_size, void* d_ws, size_t ws_size,
                              hipStream_t stream) {
    const float* x   = (const float*)d_in[0];
    const float* z_q = (const float*)d_in[1];
    const float* b_q = (const float*)d_in[2];
    const float* z_k = (const float*)d_in[3];
    const float* b_k = (const float*)d_in[4];
    const float* w_v = (const float*)d_in[5];
    const float* b_v = (const float*)d_in[6];
    float* out = (float*)d_out;

    // ws (~70MB): Pq bf16 16MB | xb 16MB (Qb aliases after GEMM) | Wcat 6MB
    //           | VT 16MB | Kb 16MB | aux.   Pk bf16 lives in d_out (scratch).
    ushort* Pq   = (ushort*)d_ws;
    ushort* xb   = Pq + NELEM;
    ushort* Qb   = xb;                               // alias: xb dead after GEMM
    ushort* Wcat = xb + NELEM;                       // [3072][1024] bf16
    ushort* VT   = Wcat + (size_t)3 * D_MODEL * D_MODEL;
    ushort* Kb   = VT + NELEM;
    float*  aux  = (float*)(Kb + NELEM);
    float*  lam  = aux + 6144;                       // 8192 floats
    ushort* Pk   = (ushort*)out;                     // d_out as scratch

    // ALL input prep in one launch (x-cast+lam, zq/zk transpose-cast, wv cast,
    // per-column Poincare constants -- now coalesced, 64 blocks instead of 2048)
    mega_prep<<<dim3(9280), 256, 0, stream>>>(x, z_q, b_q, z_k, b_k, w_v,
                                              xb, lam, Wcat, aux);

    // One fused GEMM: Q-chunk -> Pq, K-chunk -> Pk (d_out), V-chunk -> VT
    gemm_fused<<<dim3(1536), 256, 0, stream>>>(xb, Wcat, b_v, Pq, Pk, VT);

    // Fused Poincare epilogues: y=0 Q chain (scale log2e/8), y=1 K chain
    poincare_epilogue2<<<dim3(NTOK, 2), 256, 0, stream>>>(Pq, Pk, lam, aux, Qb, Kb);

    attn_mfma<<<dim3(512), 512, 0, stream>>>(Qb, Kb, VT, out);
}